// Round 4
// baseline (564.525 us; speedup 1.0000x reference)
//
#include <hip/hip_runtime.h>

typedef _Float16 half8 __attribute__((ext_vector_type(8)));
typedef float f32x16 __attribute__((ext_vector_type(16)));

// Problem constants
#define EDIM 256
#define NE   1024
#define HW   4096

// d_out layout (fp32 elements): z_q[16777216], loss, perplexity, idx[65536]
#define ZQ_OFF   0
#define LOSS_OFF 16777216
#define PERP_OFF 16777217
#define IDX_OFF  16777218

// ws layout (byte offsets)
#define WS_ESPH    0                         // eh fragment-ordered, 512 KB
#define WS_ESPL    (512*1024)                // el fragment-ordered, 512 KB
#define WS_BNORM   (1024*1024)               // 1024 f32
#define WS_COUNTS  (WS_BNORM + 4096)         // 1024 i32
#define WS_COUNTER (WS_COUNTS + 4096)        // i32 (+pad)
#define WS_LOSS    (WS_COUNTER + 16)         // double
#define WS_AN      (WS_LOSS + 16)            // 65536 f32
#define WS_IDX     (WS_AN + 65536*4)         // 65536 i32
#define WS_LIST    (WS_IDX + 65536*4)        // 65536 i32

// refine margin: covers |approx - numpy fp32| (split residual + MFMA order + an-rounding)
#define EPS 3.0e-4f
// acc holds 1024*D (e pre-scaled by 1024); 2*D = acc/512
#define SCACC (1.0f/512.0f)

// ---------------------------------------------------------------------------
// numpy pairwise_sum replica for a 128-element block of squares.
// ---------------------------------------------------------------------------
__device__ __forceinline__ float np_half128(const float* __restrict__ p, long stride) {
#pragma clang fp contract(off)
    float r[8];
#pragma unroll
    for (int j = 0; j < 8; ++j) { float v = p[(long)j * stride]; r[j] = v * v; }
    for (int i = 8; i < 128; i += 8) {
#pragma unroll
        for (int j = 0; j < 8; ++j) { float v = p[(long)(i + j) * stride]; r[j] += v * v; }
    }
    return ((r[0] + r[1]) + (r[2] + r[3])) + ((r[4] + r[5]) + (r[6] + r[7]));
}

// ---------------------------------------------------------------------------
// K0: split e*1024 into f16 hi/lo, FRAGMENT-ORDERED for 32x32x16 MFMA staging:
// chunk(jt,kc,nt,kh,hb,lm) at (((jt*8+kc)*4+nt)*2+kh)*64 + hb*32 + lm, 8 halves k-contig.
// code j = jt*128+nt*32+lm ; k = kc*32+kh*16+hb*8+kk
// ---------------------------------------------------------------------------
__global__ void k_prep_e(const float* __restrict__ e, _Float16* __restrict__ eh,
                         _Float16* __restrict__ el) {
    int t = blockIdx.x * 256 + threadIdx.x;   // 262144
    int j = t >> 8, c = t & 255;
    float v = e[t] * 1024.0f;                 // exact pow2 scale
    _Float16 h = (_Float16)v;
    _Float16 l = (_Float16)(v - (float)h);
    int jt = j >> 7, nt = (j >> 5) & 3, lm = j & 31;
    int kc = c >> 5, r = c & 31, kh = r >> 4, hb = (r >> 3) & 1, kk = r & 7;
    int chunk = (((jt * 8 + kc) * 4 + nt) * 2 + kh) * 64 + hb * 32 + lm;
    eh[chunk * 8 + kk] = h;
    el[chunk * 8 + kk] = l;
}

// ---------------------------------------------------------------------------
// K1: B_j = numpy-pairwise sum of e[j][:]^2
// ---------------------------------------------------------------------------
__global__ void k_bnorm(const float* __restrict__ e, float* __restrict__ Bn) {
    int j = blockIdx.x * 256 + threadIdx.x;   // grid 4
    const float* p = e + (size_t)j * EDIM;
    Bn[j] = np_half128(p, 1) + np_half128(p + 128, 1);
}

// ---------------------------------------------------------------------------
// K2: A_n = numpy-pairwise sum of zf[n][:]^2 ; also accumulate Sum(A_n) into
// the loss accumulator (loss = Sum A_n + Sum m1', m1' = min_j(B_j - 2 z.e_j))
// ---------------------------------------------------------------------------
__global__ void k_rownorm(const float* __restrict__ z, float* __restrict__ An,
                          double* __restrict__ loss_sum) {
    int n = blockIdx.x * 256 + threadIdx.x;   // grid 256
    int b = n >> 12, hw = n & 4095;
    const float* p = z + (size_t)b * (EDIM * HW) + hw;
    float a = np_half128(p, HW) + np_half128(p + (size_t)128 * HW, HW);
    An[n] = a;
    double s = (double)a;
#pragma unroll
    for (int sh = 1; sh < 64; sh <<= 1) s += __shfl_xor(s, sh, 64);
    if ((threadIdx.x & 63) == 0) atomicAdd(loss_sum, s);
}

// ---------------------------------------------------------------------------
// K3: MFMA distance (2-term split-f16 on 32x32x16) + top-2 argmin + loss.
// 256 blocks x 256 thr (4 waves); block = 256 rows x 1024 codes; wave = 64 rows.
// B staged in LDS double-buffered, fragment-ordered (lane-contiguous b128,
// conflict-free); one barrier per (jt,kc) iteration.
// ---------------------------------------------------------------------------
__global__ __launch_bounds__(256, 1) void k_dist(
    const float* __restrict__ z, const _Float16* __restrict__ eh,
    const _Float16* __restrict__ el, const float* __restrict__ Bn,
    int* __restrict__ idxw, float* __restrict__ out,
    int* __restrict__ counter, int* __restrict__ list,
    double* __restrict__ loss_sum)
{
    __shared__ uint4 sB[2][1024];   // [buf][ H 512 chunks | L 512 chunks ], 32 KB

    const int t  = threadIdx.x;
    const int w  = t >> 6;
    const int L  = t & 63;
    const int l5 = L & 31;
    const int hb = L >> 5;
    const int n0 = blockIdx.x * 256;          // 256 blocks
    const int b  = n0 >> 12, hw0 = n0 & 4095;
    const float* zb = z + (size_t)b * (EDIM * HW) + hw0;
    const int rbase = w * 64;

    // A fragments: Ah[mt][ks], lane holds A[m = rbase+mt*32+l5][k = ks*16+hb*8+j]
    half8 Ah[2][16];
#pragma unroll
    for (int mt = 0; mt < 2; ++mt) {
        int m = rbase + mt * 32 + l5;
#pragma unroll
        for (int ks = 0; ks < 16; ++ks) {
            float av[8];
#pragma unroll
            for (int j = 0; j < 8; ++j)
                av[j] = zb[(ks * 16 + hb * 8 + j) * HW + m];
#pragma unroll
            for (int j = 0; j < 8; ++j)
                Ah[mt][ks][j] = (_Float16)av[j];
        }
    }

    f32x16 acc[2][4];
#pragma unroll
    for (int mt = 0; mt < 2; ++mt)
#pragma unroll
        for (int nt = 0; nt < 4; ++nt)
#pragma unroll
            for (int r = 0; r < 16; ++r) acc[mt][nt][r] = 0.f;

    float m1[32], m2[32]; int i1[32];
#pragma unroll
    for (int s = 0; s < 32; ++s) { m1[s] = 1e30f; m2[s] = 1e30f; i1[s] = 0; }

    const uint4* gh = (const uint4*)eh;
    const uint4* gl = (const uint4*)el;

    // prologue: stage iter 0 into buf 0
    {
        uint4 h0 = gh[t], h1 = gh[t + 256];
        uint4 l0 = gl[t], l1 = gl[t + 256];
        sB[0][t] = h0; sB[0][t + 256] = h1;
        sB[0][512 + t] = l0; sB[0][512 + 256 + t] = l1;
    }
    __syncthreads();

    for (int it = 0; it < 64; ++it) {
        const int buf = it & 1;
        uint4 h0, h1, l0, l1;
        if (it < 63) {
            int src = (it + 1) * 512 + t;
            h0 = gh[src]; h1 = gh[src + 256];
            l0 = gl[src]; l1 = gl[src + 256];
        }

        // compute: 16 conflict-free b128 reads + 32 MFMAs
        const int kc = it & 7;
#pragma unroll
        for (int kh = 0; kh < 2; ++kh) {
            const int ks = kc * 2 + kh;
#pragma unroll
            for (int nt = 0; nt < 4; ++nt) {
                int idx = (nt * 2 + kh) * 64 + L;
                half8 bh = *(const half8*)&sB[buf][idx];
                half8 bl = *(const half8*)&sB[buf][512 + idx];
#pragma unroll
                for (int mt = 0; mt < 2; ++mt) {
                    acc[mt][nt] = __builtin_amdgcn_mfma_f32_32x32x16_f16(Ah[mt][ks], bh, acc[mt][nt], 0, 0, 0);
                    acc[mt][nt] = __builtin_amdgcn_mfma_f32_32x32x16_f16(Ah[mt][ks], bl, acc[mt][nt], 0, 0, 0);
                }
            }
        }

        // end of jt: fold acc -> top2, reset acc
        if (kc == 7) {
            const int jt = it >> 3;
#pragma unroll
            for (int nt = 0; nt < 4; ++nt) {
                float en = Bn[jt * 128 + nt * 32 + l5];
                int jc = jt * 128 + nt * 32 + l5;
#pragma unroll
                for (int mt = 0; mt < 2; ++mt) {
#pragma unroll
                    for (int r = 0; r < 16; ++r) {
                        float d = en - acc[mt][nt][r] * SCACC;
                        int slot = mt * 16 + r;
                        if (d < m1[slot]) { m2[slot] = m1[slot]; m1[slot] = d; i1[slot] = jc; }
                        else if (d < m2[slot]) m2[slot] = d;
                        acc[mt][nt][r] = 0.f;
                    }
                }
            }
        }

        if (it < 63) {
            sB[buf ^ 1][t] = h0; sB[buf ^ 1][t + 256] = h1;
            sB[buf ^ 1][512 + t] = l0; sB[buf ^ 1][512 + 256 + t] = l1;
        }
        __syncthreads();
    }

    // cross-lane top2 merge over the 32 lanes (same rows share L>>5 and differ in l5)
    double lossP = 0.0;
#pragma unroll
    for (int slot = 0; slot < 32; ++slot) {
        float v1 = m1[slot], v2 = m2[slot]; int ii = i1[slot];
#pragma unroll
        for (int s = 1; s < 32; s <<= 1) {
            float o1 = __shfl_xor(v1, s, 64);
            int   oi = __shfl_xor(ii, s, 64);
            float o2 = __shfl_xor(v2, s, 64);
            float hi = fmaxf(v1, o1);
            if (o1 < v1 || (o1 == v1 && oi < ii)) { v1 = o1; ii = oi; }
            v2 = fminf(fminf(v2, o2), hi);
        }
        if (l5 == 0) {
            int mt = slot >> 4, r = slot & 15;
            int rloc = rbase + mt * 32 + 4 * hb + (r & 3) + 8 * (r >> 2);
            int n = n0 + rloc;
            idxw[n] = ii;
            out[IDX_OFF + n] = (float)ii;
            lossP += (double)v1;
            if (v2 - v1 < EPS) {
                int p = atomicAdd(counter, 1);
                if (p < 65536) list[p] = n;
            }
        }
    }
    if (l5 == 0) atomicAdd(loss_sum, lossP);
}

// ---------------------------------------------------------------------------
// K4: numpy-bit-faithful fp32 full rescan of flagged rows (16 rows/block-iter).
// ---------------------------------------------------------------------------
__global__ void k_refine(const float* __restrict__ z, const float* __restrict__ e,
                         const float* __restrict__ Bn, const float* __restrict__ An,
                         const int* __restrict__ counter, const int* __restrict__ list,
                         int* __restrict__ idxw, float* __restrict__ out)
{
    __shared__ float zs[16][256];
    __shared__ int   ns[16];
    __shared__ float ans[16];
    __shared__ float pv[4][16];
    __shared__ int   pi[4][16];
    int t = threadIdx.x;
    int cnt = min(*counter, 65536);
    for (int li0 = blockIdx.x * 16; li0 < cnt; li0 += gridDim.x * 16) {
        int nrows = min(16, cnt - li0);
        __syncthreads();
        if (t < 16) {
            int n = (t < nrows) ? list[li0 + t] : list[li0];
            ns[t] = n; ans[t] = An[n];
        }
        __syncthreads();
        for (int u = 0; u < 16; ++u) {
            int n = ns[u];
            zs[u][t] = z[(size_t)(n >> 12) * (EDIM * HW) + (n & 4095) + t * HW];
        }
        __syncthreads();

        float bm[16]; int bi[16];
#pragma unroll
        for (int r = 0; r < 16; ++r) { bm[r] = 1e30f; bi[r] = 1 << 30; }
        for (int p = 0; p < 4; ++p) {
            int j = t + p * 256;
            const float* er = e + (size_t)j * EDIM;
            float D[16];
#pragma unroll
            for (int r = 0; r < 16; ++r) D[r] = 0.f;
            for (int c = 0; c < 256; ++c) {
                float ev = er[c];
#pragma unroll
                for (int r = 0; r < 16; ++r)
                    D[r] = __builtin_fmaf(ev, zs[r][c], D[r]);
            }
            float bnj = Bn[j];
            {
#pragma clang fp contract(off)
#pragma unroll
                for (int r = 0; r < 16; ++r) {
                    float t2 = D[r] + D[r];
                    float s  = ans[r] + bnj;
                    float d  = s - t2;
                    if (d < bm[r]) { bm[r] = d; bi[r] = j; }
                }
            }
        }
        int wv = t >> 6, L = t & 63;
        for (int r = 0; r < 16; ++r) {
            float v = bm[r]; int ii = bi[r];
#pragma unroll
            for (int s = 1; s < 64; s <<= 1) {
                float ov = __shfl_xor(v, s, 64);
                int   oi = __shfl_xor(ii, s, 64);
                if (ov < v || (ov == v && oi < ii)) { v = ov; ii = oi; }
            }
            if (L == 0) { pv[wv][r] = v; pi[wv][r] = ii; }
        }
        __syncthreads();
        if (t < nrows) {
            float v = pv[0][t]; int ii = pi[0][t];
#pragma unroll
            for (int w2 = 1; w2 < 4; ++w2)
                if (pv[w2][t] < v || (pv[w2][t] == v && pi[w2][t] < ii)) { v = pv[w2][t]; ii = pi[w2][t]; }
            int n = ns[t];
            idxw[n] = ii;
            out[IDX_OFF + n] = (float)ii;
        }
    }
}

// ---------------------------------------------------------------------------
// K5: histogram of final idx
// ---------------------------------------------------------------------------
__global__ void k_hist(const int* __restrict__ idxw, int* __restrict__ counts) {
    int t = blockIdx.x * 256 + threadIdx.x;   // grid 256
    atomicAdd(&counts[idxw[t]], 1);
}

// ---------------------------------------------------------------------------
// K6: zq gather/scatter only (loss computed via distance identity in k_dist).
// grid 512: (rowgroup, c-half). float4 writes, LDS-transposed e staging.
// ---------------------------------------------------------------------------
__global__ void k_gather(const float* __restrict__ e, const int* __restrict__ idxw,
                         float* __restrict__ out) {
    __shared__ int   jrow[256];
    __shared__ float Ls[8][260];
    int t = threadIdx.x;
    int rg = blockIdx.x >> 1, ch = blockIdx.x & 1;
    int n0 = rg * 256;
    int b = n0 >> 12, hw0 = n0 & 4095;
    jrow[t] = idxw[n0 + t];
    float* zqb = out + ZQ_OFF + (size_t)b * (EDIM * HW) + hw0 + (size_t)ch * 128 * HW;
    int w = t >> 6, L = t & 63;
    __syncthreads();

    for (int cc = 0; cc < 16; ++cc) {
        const float4* ep = (const float4*)(e + (size_t)jrow[t] * EDIM + ch * 128 + cc * 8);
        float4 v0 = ep[0], v1 = ep[1];
        Ls[0][t] = v0.x; Ls[1][t] = v0.y; Ls[2][t] = v0.z; Ls[3][t] = v0.w;
        Ls[4][t] = v1.x; Ls[5][t] = v1.y; Ls[6][t] = v1.z; Ls[7][t] = v1.w;
        __syncthreads();
#pragma unroll
        for (int i = 0; i < 2; ++i) {
            int c = w * 2 + i;
            float4 vv = *(const float4*)&Ls[c][L * 4];
            *(float4*)(zqb + (size_t)(cc * 8 + c) * HW + L * 4) = vv;
        }
        __syncthreads();
    }
}

// ---------------------------------------------------------------------------
// K7: finalize scalars
// ---------------------------------------------------------------------------
__global__ void k_final(const int* __restrict__ counts, const double* __restrict__ loss_sum,
                        float* __restrict__ out) {
    __shared__ float sred[4];
    int t = threadIdx.x;
    float s = 0.f;
    for (int qq = 0; qq < 4; ++qq) {
        float p = (float)counts[qq * 256 + t] * (1.0f / 65536.0f);
        s += p * logf(p + 1e-10f);
    }
#pragma unroll
    for (int sh = 1; sh < 64; sh <<= 1) s += __shfl_xor(s, sh, 64);
    if ((t & 63) == 0) sred[t >> 6] = s;
    __syncthreads();
    if (t == 0) {
        out[PERP_OFF] = expf(-(sred[0] + sred[1] + sred[2] + sred[3]));
        out[LOSS_OFF] = (float)(*loss_sum * 1.25 / 16777216.0);
    }
}

extern "C" void kernel_launch(void* const* d_in, const int* in_sizes, int n_in,
                              void* d_out, int out_size, void* d_ws, size_t ws_size,
                              hipStream_t stream) {
    const float* z = (const float*)d_in[0];
    const float* e = (const float*)d_in[1];
    float* out = (float*)d_out;
    char* ws = (char*)d_ws;

    _Float16* eh      = (_Float16*)(ws + WS_ESPH);
    _Float16* el      = (_Float16*)(ws + WS_ESPL);
    float*    Bn      = (float*)(ws + WS_BNORM);
    int*      counts  = (int*)(ws + WS_COUNTS);
    int*      counter = (int*)(ws + WS_COUNTER);
    double*   loss_sum= (double*)(ws + WS_LOSS);
    float*    An      = (float*)(ws + WS_AN);
    int*      idxw    = (int*)(ws + WS_IDX);
    int*      list    = (int*)(ws + WS_LIST);

    // zero counts + counter + loss accumulator (contiguous)
    hipMemsetAsync(ws + WS_COUNTS, 0, 4096 + 16 + 16, stream);

    k_prep_e <<<1024, 256, 0, stream>>>(e, eh, el);
    k_bnorm  <<<4,    256, 0, stream>>>(e, Bn);
    k_rownorm<<<256,  256, 0, stream>>>(z, An, loss_sum);
    k_dist   <<<256,  256, 0, stream>>>(z, eh, el, Bn, idxw, out, counter, list, loss_sum);
    k_refine <<<256,  256, 0, stream>>>(z, e, Bn, An, counter, list, idxw, out);
    k_hist   <<<256,  256, 0, stream>>>(idxw, counts);
    k_gather <<<512,  256, 0, stream>>>(e, idxw, out);
    k_final  <<<1,    256, 0, stream>>>(counts, loss_sum, out);
}

// Round 5
// 424.451 us; speedup vs baseline: 1.3300x; 1.3300x over previous
//
#include <hip/hip_runtime.h>

typedef _Float16 half8 __attribute__((ext_vector_type(8)));
typedef float f32x16 __attribute__((ext_vector_type(16)));

// Problem constants
#define EDIM 256
#define NE   1024
#define HW   4096

// d_out layout (fp32 elements): z_q[16777216], loss, perplexity, idx[65536]
#define ZQ_OFF   0
#define LOSS_OFF 16777216
#define PERP_OFF 16777217
#define IDX_OFF  16777218

// ws layout (byte offsets)
#define WS_ESPH    0                         // eh fragment-ordered f16, 512 KB
#define WS_BNORM   (1024*1024)               // 1024 f32
#define WS_COUNTS  (WS_BNORM + 4096)         // 1024 i32
#define WS_COUNTER (WS_COUNTS + 4096)        // i32 (+pad)
#define WS_LOSS    (WS_COUNTER + 16)         // double
#define WS_AN      (WS_LOSS + 16)            // 65536 f32
#define WS_IDX     (WS_AN + 65536*4)         // 65536 i32
#define WS_LIST    (WS_IDX + 65536*4)        // 65536 i32

// refine margin in d-units; provable distortion bound ~1.9e-4 (single-term
// split residual 9.6e-5 + numpy fp32 rounding 9.2e-5). 1.6x safety.
#define EPS 3.0e-4f
// g = acc - 512*B_j tracked in max-domain; gap test g1-g2 < 512*EPS
#define GEPS (512.0f * EPS)

// ---------------------------------------------------------------------------
// numpy pairwise_sum replica for a 128-element block of squares.
// ---------------------------------------------------------------------------
__device__ __forceinline__ float np_half128(const float* __restrict__ p, long stride) {
#pragma clang fp contract(off)
    float r[8];
#pragma unroll
    for (int j = 0; j < 8; ++j) { float v = p[(long)j * stride]; r[j] = v * v; }
    for (int i = 8; i < 128; i += 8) {
#pragma unroll
        for (int j = 0; j < 8; ++j) { float v = p[(long)(i + j) * stride]; r[j] += v * v; }
    }
    return ((r[0] + r[1]) + (r[2] + r[3])) + ((r[4] + r[5]) + (r[6] + r[7]));
}

// ---------------------------------------------------------------------------
// K0: e*1024 -> f16 hi, FRAGMENT-ORDERED for 32x32x16 MFMA staging.
// chunk(jt,kc,nt,kh) holds 64 lanes x 8 halves; code j = jt*128+nt*32+lm,
// k = kc*32+kh*16+hb*8+kk.
// ---------------------------------------------------------------------------
__global__ void k_prep_e(const float* __restrict__ e, _Float16* __restrict__ eh) {
    int t = blockIdx.x * 256 + threadIdx.x;   // 262144
    int j = t >> 8, c = t & 255;
    float v = e[t] * 1024.0f;                 // exact pow2 scale
    _Float16 h = (_Float16)v;
    int jt = j >> 7, nt = (j >> 5) & 3, lm = j & 31;
    int kc = c >> 5, r = c & 31, kh = r >> 4, hb = (r >> 3) & 1, kk = r & 7;
    int chunk = (((jt * 8 + kc) * 4 + nt) * 2 + kh) * 64 + hb * 32 + lm;
    eh[chunk * 8 + kk] = h;
}

// ---------------------------------------------------------------------------
// K1: B_j = numpy-pairwise sum of e[j][:]^2
// ---------------------------------------------------------------------------
__global__ void k_bnorm(const float* __restrict__ e, float* __restrict__ Bn) {
    int j = blockIdx.x * 256 + threadIdx.x;   // grid 4
    const float* p = e + (size_t)j * EDIM;
    Bn[j] = np_half128(p, 1) + np_half128(p + 128, 1);
}

// ---------------------------------------------------------------------------
// K2: A_n = numpy-pairwise sum of zf[n][:]^2 ; accumulate Sum(A_n) into loss
// (loss = Sum A_n + Sum min_j(B_j - 2 z.e_j))
// ---------------------------------------------------------------------------
__global__ void k_rownorm(const float* __restrict__ z, float* __restrict__ An,
                          double* __restrict__ loss_sum) {
    int n = blockIdx.x * 256 + threadIdx.x;   // grid 256
    int b = n >> 12, hw = n & 4095;
    const float* p = z + (size_t)b * (EDIM * HW) + hw;
    float a = np_half128(p, HW) + np_half128(p + (size_t)128 * HW, HW);
    An[n] = a;
    double s = (double)a;
#pragma unroll
    for (int sh = 1; sh < 64; sh <<= 1) s += __shfl_xor(s, sh, 64);
    if ((threadIdx.x & 63) == 0) atomicAdd(loss_sum, s);
}

// ---------------------------------------------------------------------------
// K3: single-term f16 MFMA distance + top-2 argmin + loss + histogram.
// 512 blocks x 256 thr (4 waves x 32 rows = 128 rows/block) -> 2 waves/SIMD.
// B-hi streamed through 16KB double-buffered LDS (depth-2 register prefetch,
// one barrier/iter). Max-domain tracking: g = acc - 512*B_j; argmin d = argmax g.
// ---------------------------------------------------------------------------
__global__ __launch_bounds__(256, 2) void k_dist(
    const float* __restrict__ z, const _Float16* __restrict__ eh,
    const float* __restrict__ Bn, int* __restrict__ idxw,
    float* __restrict__ out, int* __restrict__ counter, int* __restrict__ list,
    double* __restrict__ loss_sum, int* __restrict__ counts)
{
    __shared__ uint4 sB[2][512];   // 2 x 8 KB

    const int t  = threadIdx.x;
    const int w  = t >> 6;
    const int L  = t & 63;
    const int l5 = L & 31;
    const int hb = L >> 5;
    const int n0 = blockIdx.x * 128;          // 512 blocks
    const int b  = n0 >> 12, hw0 = n0 & 4095;
    const float* zb = z + (size_t)b * (EDIM * HW) + hw0;
    const int rbase = w * 32;

    // A fragments (hi only): lane holds A[m=rbase+l5][k=ks*16+hb*8+j]
    half8 Ah[16];
    {
        int m = rbase + l5;
#pragma unroll
        for (int ks = 0; ks < 16; ++ks) {
            float av[8];
#pragma unroll
            for (int j = 0; j < 8; ++j)
                av[j] = zb[(ks * 16 + hb * 8 + j) * HW + m];
#pragma unroll
            for (int j = 0; j < 8; ++j)
                Ah[ks][j] = (_Float16)av[j];
        }
    }

    f32x16 acc[4];
#pragma unroll
    for (int nt = 0; nt < 4; ++nt)
#pragma unroll
        for (int r = 0; r < 16; ++r) acc[nt][r] = 0.f;

    float g1[16], g2[16]; int i1[16];
#pragma unroll
    for (int r = 0; r < 16; ++r) { g1[r] = -1e30f; g2[r] = -1e30f; i1[r] = 0; }

    const uint4* gB = (const uint4*)eh;

    // depth-2 register prefetch pipeline
    uint4 pa0, pa1, pb0, pb1;
    pa0 = gB[t];        pa1 = gB[t + 256];        // iter 0
    pb0 = gB[t + 512];  pb1 = gB[t + 768];        // iter 1
    sB[0][t] = pa0; sB[0][t + 256] = pa1;
    pa0 = gB[t + 1024]; pa1 = gB[t + 1280];       // iter 2
    __syncthreads();

    for (int it = 0; it < 64; ++it) {
        const int buf = it & 1;
        // compute: 8 conflict-free ds_read_b128 + 8 MFMA
#pragma unroll
        for (int kh = 0; kh < 2; ++kh) {
            const int ks = (it & 7) * 2 + kh;
#pragma unroll
            for (int nt = 0; nt < 4; ++nt) {
                half8 bh = *(const half8*)&sB[buf][(nt * 2 + kh) * 64 + L];
                acc[nt] = __builtin_amdgcn_mfma_f32_32x32x16_f16(Ah[ks], bh, acc[nt], 0, 0, 0);
            }
        }

        // end of jt: fold acc -> top2 (max domain), reset acc
        if ((it & 7) == 7) {
            const int jt = it >> 3;
            float en512[4];
#pragma unroll
            for (int nt = 0; nt < 4; ++nt)
                en512[nt] = 512.0f * Bn[jt * 128 + nt * 32 + l5];
#pragma unroll
            for (int nt = 0; nt < 4; ++nt) {
                int jc = jt * 128 + nt * 32 + l5;
#pragma unroll
                for (int r = 0; r < 16; ++r) {
                    float v = acc[nt][r] - en512[nt];
                    g2[r] = fmaxf(g2[r], fminf(v, g1[r]));   // 2nd-largest
                    bool gt = v > g1[r];                     // strict: first idx wins
                    g1[r] = fmaxf(v, g1[r]);
                    i1[r] = gt ? jc : i1[r];
                    acc[nt][r] = 0.f;
                }
            }
        }

        // stage next iter, prefetch it+3
        if (it < 63) {
            if ((it & 1) == 0) {
                sB[buf ^ 1][t] = pb0; sB[buf ^ 1][t + 256] = pb1;
                if (it + 3 < 64) { int q = (it + 3) * 512; pb0 = gB[q + t]; pb1 = gB[q + t + 256]; }
            } else {
                sB[buf ^ 1][t] = pa0; sB[buf ^ 1][t + 256] = pa1;
                if (it + 3 < 64) { int q = (it + 3) * 512; pa0 = gB[q + t]; pa1 = gB[q + t + 256]; }
            }
        }
        __syncthreads();
    }

    // cross-lane top2 merge over 32 lanes sharing rows (same hb)
    double lossP = 0.0;
#pragma unroll
    for (int r = 0; r < 16; ++r) {
        float v1 = g1[r], v2 = g2[r]; int ii = i1[r];
#pragma unroll
        for (int s = 1; s < 32; s <<= 1) {
            float o1 = __shfl_xor(v1, s, 64);
            int   oi = __shfl_xor(ii, s, 64);
            float o2 = __shfl_xor(v2, s, 64);
            float lo = fminf(v1, o1);
            if (o1 > v1 || (o1 == v1 && oi < ii)) { v1 = o1; ii = oi; }
            v2 = fmaxf(fmaxf(v2, o2), lo);
        }
        if (l5 == 0) {
            int rloc = rbase + 4 * hb + (r & 3) + 8 * (r >> 2);
            int n = n0 + rloc;
            idxw[n] = ii;
            out[IDX_OFF + n] = (float)ii;
            atomicAdd(&counts[ii], 1);
            lossP += -(double)v1 * (1.0 / 512.0);   // d_min = -g1/512
            if (v1 - v2 < GEPS) {
                int p = atomicAdd(counter, 1);
                if (p < 65536) list[p] = n;
            }
        }
    }
    if (l5 == 0) atomicAdd(loss_sum, lossP);
}

// ---------------------------------------------------------------------------
// K4: numpy-bit-faithful fp32 rescan of flagged rows + histogram delta-fix.
// ---------------------------------------------------------------------------
__global__ void k_refine(const float* __restrict__ z, const float* __restrict__ e,
                         const float* __restrict__ Bn, const float* __restrict__ An,
                         const int* __restrict__ counter, const int* __restrict__ list,
                         int* __restrict__ idxw, float* __restrict__ out,
                         int* __restrict__ counts)
{
    __shared__ float zs[16][256];
    __shared__ int   ns[16];
    __shared__ float ans[16];
    __shared__ float pv[4][16];
    __shared__ int   pi[4][16];
    int t = threadIdx.x;
    int cnt = min(*counter, 65536);
    for (int li0 = blockIdx.x * 16; li0 < cnt; li0 += gridDim.x * 16) {
        int nrows = min(16, cnt - li0);
        __syncthreads();
        if (t < 16) {
            int n = (t < nrows) ? list[li0 + t] : list[li0];
            ns[t] = n; ans[t] = An[n];
        }
        __syncthreads();
        for (int u = 0; u < 16; ++u) {
            int n = ns[u];
            zs[u][t] = z[(size_t)(n >> 12) * (EDIM * HW) + (n & 4095) + t * HW];
        }
        __syncthreads();

        float bm[16]; int bi[16];
#pragma unroll
        for (int r = 0; r < 16; ++r) { bm[r] = 1e30f; bi[r] = 1 << 30; }
        for (int p = 0; p < 4; ++p) {
            int j = t + p * 256;
            const float* er = e + (size_t)j * EDIM;
            float D[16];
#pragma unroll
            for (int r = 0; r < 16; ++r) D[r] = 0.f;
            for (int c = 0; c < 256; ++c) {
                float ev = er[c];
#pragma unroll
                for (int r = 0; r < 16; ++r)
                    D[r] = __builtin_fmaf(ev, zs[r][c], D[r]);
            }
            float bnj = Bn[j];
            {
#pragma clang fp contract(off)
#pragma unroll
                for (int r = 0; r < 16; ++r) {
                    float t2 = D[r] + D[r];
                    float s  = ans[r] + bnj;
                    float d  = s - t2;
                    if (d < bm[r]) { bm[r] = d; bi[r] = j; }
                }
            }
        }
        int wv = t >> 6, L = t & 63;
        for (int r = 0; r < 16; ++r) {
            float v = bm[r]; int ii = bi[r];
#pragma unroll
            for (int s = 1; s < 64; s <<= 1) {
                float ov = __shfl_xor(v, s, 64);
                int   oi = __shfl_xor(ii, s, 64);
                if (ov < v || (ov == v && oi < ii)) { v = ov; ii = oi; }
            }
            if (L == 0) { pv[wv][r] = v; pi[wv][r] = ii; }
        }
        __syncthreads();
        if (t < nrows) {
            float v = pv[0][t]; int ii = pi[0][t];
#pragma unroll
            for (int w2 = 1; w2 < 4; ++w2)
                if (pv[w2][t] < v || (pv[w2][t] == v && pi[w2][t] < ii)) { v = pv[w2][t]; ii = pi[w2][t]; }
            int n = ns[t];
            int old = idxw[n];
            if (old != ii) {
                idxw[n] = ii;
                out[IDX_OFF + n] = (float)ii;
                atomicSub(&counts[old], 1);
                atomicAdd(&counts[ii], 1);
            }
        }
    }
}

// ---------------------------------------------------------------------------
// K5: zq gather/scatter (loss via distance identity; idx final post-refine).
// ---------------------------------------------------------------------------
__global__ void k_gather(const float* __restrict__ e, const int* __restrict__ idxw,
                         float* __restrict__ out) {
    __shared__ int   jrow[256];
    __shared__ float Ls[8][260];
    int t = threadIdx.x;
    int rg = blockIdx.x >> 1, ch = blockIdx.x & 1;
    int n0 = rg * 256;
    int b = n0 >> 12, hw0 = n0 & 4095;
    jrow[t] = idxw[n0 + t];
    float* zqb = out + ZQ_OFF + (size_t)b * (EDIM * HW) + hw0 + (size_t)ch * 128 * HW;
    int w = t >> 6, L = t & 63;
    __syncthreads();

    for (int cc = 0; cc < 16; ++cc) {
        const float4* ep = (const float4*)(e + (size_t)jrow[t] * EDIM + ch * 128 + cc * 8);
        float4 v0 = ep[0], v1 = ep[1];
        Ls[0][t] = v0.x; Ls[1][t] = v0.y; Ls[2][t] = v0.z; Ls[3][t] = v0.w;
        Ls[4][t] = v1.x; Ls[5][t] = v1.y; Ls[6][t] = v1.z; Ls[7][t] = v1.w;
        __syncthreads();
#pragma unroll
        for (int i = 0; i < 2; ++i) {
            int c = w * 2 + i;
            float4 vv = *(const float4*)&Ls[c][L * 4];
            *(float4*)(zqb + (size_t)(cc * 8 + c) * HW + L * 4) = vv;
        }
        __syncthreads();
    }
}

// ---------------------------------------------------------------------------
// K6: finalize scalars
// ---------------------------------------------------------------------------
__global__ void k_final(const int* __restrict__ counts, const double* __restrict__ loss_sum,
                        float* __restrict__ out) {
    __shared__ float sred[4];
    int t = threadIdx.x;
    float s = 0.f;
    for (int qq = 0; qq < 4; ++qq) {
        float p = (float)counts[qq * 256 + t] * (1.0f / 65536.0f);
        s += p * logf(p + 1e-10f);
    }
#pragma unroll
    for (int sh = 1; sh < 64; sh <<= 1) s += __shfl_xor(s, sh, 64);
    if ((t & 63) == 0) sred[t >> 6] = s;
    __syncthreads();
    if (t == 0) {
        out[PERP_OFF] = expf(-(sred[0] + sred[1] + sred[2] + sred[3]));
        out[LOSS_OFF] = (float)(*loss_sum * 1.25 / 16777216.0);
    }
}

extern "C" void kernel_launch(void* const* d_in, const int* in_sizes, int n_in,
                              void* d_out, int out_size, void* d_ws, size_t ws_size,
                              hipStream_t stream) {
    const float* z = (const float*)d_in[0];
    const float* e = (const float*)d_in[1];
    float* out = (float*)d_out;
    char* ws = (char*)d_ws;

    _Float16* eh      = (_Float16*)(ws + WS_ESPH);
    float*    Bn      = (float*)(ws + WS_BNORM);
    int*      counts  = (int*)(ws + WS_COUNTS);
    int*      counter = (int*)(ws + WS_COUNTER);
    double*   loss_sum= (double*)(ws + WS_LOSS);
    float*    An      = (float*)(ws + WS_AN);
    int*      idxw    = (int*)(ws + WS_IDX);
    int*      list    = (int*)(ws + WS_LIST);

    // zero counts + counter + loss accumulator (contiguous)
    hipMemsetAsync(ws + WS_COUNTS, 0, 4096 + 16 + 16, stream);

    k_prep_e <<<1024, 256, 0, stream>>>(e, eh);
    k_bnorm  <<<4,    256, 0, stream>>>(e, Bn);
    k_rownorm<<<256,  256, 0, stream>>>(z, An, loss_sum);
    k_dist   <<<512,  256, 0, stream>>>(z, eh, Bn, idxw, out, counter, list, loss_sum, counts);
    k_refine <<<256,  256, 0, stream>>>(z, e, Bn, An, counter, list, idxw, out, counts);
    k_gather <<<512,  256, 0, stream>>>(e, idxw, out);
    k_final  <<<1,    256, 0, stream>>>(counts, loss_sum, out);
}